// Round 14
// baseline (988.382 us; speedup 1.0000x reference)
//
#include <hip/hip_runtime.h>
#include <math.h>

#define N_NODES 40000
#define N_EDGES 512000
#define SDIM 128
#define EDIM 128
#define HID 64
#define DEPTH 4
#define MSG_IN 386   // 2*SDIM + EDIM + 2
#define SCAL_IN 192  // SDIM + HID
#define CUTOFF 5.0f
#define EPS_D 1e-6f

#define TILE_M 16
#define EW 8
#define ETHREADS 512
#define EBLOCKS 256
#define TWAVES (EBLOCKS * EW)
#define NTILES (N_EDGES / TILE_M)   // 32000
#define ATILES (N_NODES / TILE_M)   // 2500
#define SCAN_B 1024
#define SCAN_NB ((N_NODES + SCAN_B - 1) / SCAN_B)   // 40

typedef __attribute__((ext_vector_type(8))) short short8;
typedef __attribute__((ext_vector_type(4))) float f32x4;
typedef unsigned long long ull;

__device__ __forceinline__ float silu_f(float x) { return x / (1.0f + __expf(-x)); }

// native cast -> compiler emits v_cvt_pk_bf16_f32 for adjacent pairs (RNE)
__device__ __forceinline__ unsigned short f2b(float x) {
  union { __bf16 b; unsigned short u; } v;
  v.b = (__bf16)x;
  return v.u;
}

__device__ __forceinline__ float b2f(unsigned short u) {
  union { unsigned int u32; float f; } v; v.u32 = (unsigned int)u << 16; return v.f;
}

__device__ __forceinline__ short8 pack8(f32x4 lo, f32x4 hi) {
  union { unsigned short u[8]; short8 s; } pk;
  pk.u[0] = f2b(lo[0]); pk.u[1] = f2b(lo[1]); pk.u[2] = f2b(lo[2]); pk.u[3] = f2b(lo[3]);
  pk.u[4] = f2b(hi[0]); pk.u[5] = f2b(hi[1]); pk.u[6] = f2b(hi[2]); pk.u[7] = f2b(hi[3]);
  return pk.s;
}

__global__ __launch_bounds__(256) void k_zero(float* __restrict__ p, int n) {
  int i = blockIdx.x * 256 + threadIdx.x;
  int stride = gridDim.x * 256;
  for (; i < n; i += stride) p[i] = 0.0f;
}

__global__ __launch_bounds__(256) void k_cnt(const int* __restrict__ dst,
                                             int* __restrict__ cnt, int ne) {
  int i = blockIdx.x * 256 + threadIdx.x;
  if (i < ne) atomicAdd(&cnt[dst[i]], 1);
}

__global__ __launch_bounds__(256) void k_deginv_cnt(const int* __restrict__ cnt,
                                                    float* __restrict__ deginv, int n) {
  int i = blockIdx.x * 256 + threadIdx.x;
  if (i < n) deginv[i] = 1.0f / fmaxf((float)cnt[i], 1.0f);
}

__global__ __launch_bounds__(256) void k_scan1(const int* __restrict__ cnt,
                                               int* __restrict__ bstart,
                                               int* __restrict__ bsum, int n) {
  __shared__ int tmp[SCAN_B];
  const int base = blockIdx.x * SCAN_B;
  const int tid = threadIdx.x;
  for (int i = tid; i < SCAN_B; i += 256)
    tmp[i] = (base + i < n) ? cnt[base + i] : 0;
  __syncthreads();
  for (int off = 1; off < SCAN_B; off <<= 1) {
    int vals[4];
#pragma unroll
    for (int j = 0; j < 4; ++j) {
      const int i = tid + j * 256;
      vals[j] = (i >= off) ? tmp[i - off] : 0;
    }
    __syncthreads();
#pragma unroll
    for (int j = 0; j < 4; ++j) tmp[tid + j * 256] += vals[j];
    __syncthreads();
  }
  for (int i = tid; i < SCAN_B; i += 256)
    if (base + i < n) bstart[base + i] = tmp[i] - cnt[base + i];
  if (tid == 0) bsum[blockIdx.x] = tmp[SCAN_B - 1];
}

__global__ void k_scan2(int* __restrict__ bsum, int nb) {
  if (threadIdx.x == 0) {
    int run = 0;
    for (int i = 0; i < nb; ++i) { const int v = bsum[i]; bsum[i] = run; run += v; }
  }
}

__global__ __launch_bounds__(256) void k_scan3(int* __restrict__ bstart,
                                               const int* __restrict__ bsum,
                                               int* __restrict__ cursor, int n) {
  int i = blockIdx.x * 256 + threadIdx.x;
  if (i < n) {
    const int v = bstart[i] + bsum[i >> 10];
    bstart[i] = v;
    cursor[i] = v;
  }
}

__global__ __launch_bounds__(256) void k_scatter(const int* __restrict__ srcs,
                                                 const int* __restrict__ dsts,
                                                 const float* __restrict__ ead,
                                                 int* __restrict__ cursor,
                                                 int4* __restrict__ meta, int ne) {
  int i = blockIdx.x * 256 + threadIdx.x;
  if (i < ne) {
    const int d = dsts[i];
    const int pos = atomicAdd(&cursor[d], 1);
    int4 m;
    m.x = i; m.y = srcs[i]; m.z = d; m.w = __float_as_int(ead[i]);
    meta[pos] = m;
  }
}

__global__ __launch_bounds__(256) void k_prep(const int4* __restrict__ meta,
                                              const float* __restrict__ vbuf,
                                              float4* __restrict__ dynA,
                                              float* __restrict__ dynB, int ne) {
  int i = blockIdx.x * 256 + threadIdx.x;
  if (i < ne) {
    const int4 m = meta[i];
    const float dx = vbuf[m.y * 3 + 0] - vbuf[m.z * 3 + 0];
    const float dy = vbuf[m.y * 3 + 1] - vbuf[m.z * 3 + 1];
    const float dz = vbuf[m.y * 3 + 2] - vbuf[m.z * 3 + 2];
    const float dist = sqrtf(dx * dx + dy * dy + dz * dz + EPS_D);
    const float cwv = (dist < CUTOFF)
                          ? 0.5f * (__cosf((float)M_PI / CUTOFF * dist) + 1.0f)
                          : 0.0f;
    dynA[i] = make_float4(dx, dy, dz, dist);
    dynB[i] = cwv;
  }
}

// ---------- MFMA Sa/Sb -> packed bf16 SaP/SbP[node][64], layout k=c*4+nt ----------
__global__ __launch_bounds__(512, 2) void k_nodeA(
    const float* __restrict__ s, const float* __restrict__ W1,
    const float* __restrict__ be1_,
    unsigned short* __restrict__ SaP, unsigned short* __restrict__ SbP) {
  __shared__ __align__(16) unsigned short W1abt[64 * 264];
  __shared__ __align__(16) unsigned short snS[EW][16 * 136];
  const int tid = threadIdx.x, lane = tid & 63, w = tid >> 6;
  const int c = lane & 15, g = lane >> 4;
  for (int idx = tid; idx < 256 * 64; idx += 512) {
    const int k = idx >> 6, n = idx & 63;
    W1abt[n * 264 + k] = f2b(W1[idx]);
  }
  __syncthreads();
  float be1_l[4];
#pragma unroll
  for (int nt = 0; nt < 4; ++nt) be1_l[nt] = be1_[nt * 16 + c];
  unsigned short* sn = snS[w];

  for (int t = blockIdx.x * EW + w; t < ATILES; t += gridDim.x * EW) {
    const int n0 = t * TILE_M;
    const f32x4* sbase = (const f32x4*)(s + (size_t)n0 * SDIM);
#pragma unroll
    for (int i = 0; i < 4; ++i) {
      const int f = i * 128 + lane * 2;
      const f32x4 a = sbase[f], b = sbase[f + 1];
      *(short8*)&sn[(i * 4 + g) * 136 + c * 8] = pack8(a, b);
    }
    f32x4 aA[4], aB[4];
#pragma unroll
    for (int nt = 0; nt < 4; ++nt) {
      aA[nt] = f32x4{be1_l[nt], be1_l[nt], be1_l[nt], be1_l[nt]};
      aB[nt] = f32x4{0.f, 0.f, 0.f, 0.f};
    }
#pragma unroll
    for (int kc = 0; kc < 4; ++kc) {
      const short8 af = *(const short8*)&sn[c * 136 + kc * 32 + g * 8];
#pragma unroll
      for (int nt = 0; nt < 4; ++nt) {
        const short8 bfA = *(const short8*)&W1abt[(nt * 16 + c) * 264 + kc * 32 + g * 8];
        const short8 bfB = *(const short8*)&W1abt[(nt * 16 + c) * 264 + 128 + kc * 32 + g * 8];
        aA[nt] = __builtin_amdgcn_mfma_f32_16x16x32_bf16(af, bfA, aA[nt], 0, 0, 0);
        aB[nt] = __builtin_amdgcn_mfma_f32_16x16x32_bf16(af, bfB, aB[nt], 0, 0, 0);
      }
    }
#pragma unroll
    for (int r = 0; r < 4; ++r) {
      const size_t row = (size_t)(n0 + g * 4 + r);
      const ull pa = (ull)f2b(aA[0][r]) | ((ull)f2b(aA[1][r]) << 16)
                   | ((ull)f2b(aA[2][r]) << 32) | ((ull)f2b(aA[3][r]) << 48);
      const ull pb = (ull)f2b(aB[0][r]) | ((ull)f2b(aB[1][r]) << 16)
                   | ((ull)f2b(aB[2][r]) << 32) | ((ull)f2b(aB[3][r]) << 48);
      *(ull*)&SaP[row * 64 + c * 4] = pa;
      *(ull*)&SbP[row * 64 + c * 4] = pb;
    }
  }
}

// ---------- MFMA node update (r10-r13 proven; f2b now native) ----------
__global__ __launch_bounds__(512, 2) void k_nodeC(
    const float* __restrict__ scur, float* __restrict__ s_dst,
    const float* __restrict__ vcur, float* __restrict__ v_dst,
    float* __restrict__ v_acc, float* __restrict__ agg,
    const float* __restrict__ deginv,
    const float* __restrict__ Ws1_, const float* __restrict__ bs1_,
    const float* __restrict__ Ws2_, const float* __restrict__ bs2_) {
  __shared__ __align__(16) unsigned short Ws1t[64 * 200];
  __shared__ __align__(16) unsigned short Ws2t[128 * 72];
  __shared__ __align__(16) unsigned short sAS[EW][16 * 200];
  __shared__ __align__(16) unsigned short hS[EW][16 * 72];
  __shared__ float dS[EW][16];
  const int tid = threadIdx.x, lane = tid & 63, w = tid >> 6;
  const int c = lane & 15, g = lane >> 4;
  for (int idx = tid; idx < 192 * 64; idx += 512) {
    const int k = idx >> 6, n = idx & 63;
    Ws1t[n * 200 + k] = f2b(Ws1_[idx]);
  }
  for (int idx = tid; idx < 64 * 128; idx += 512) {
    const int k = idx >> 7, n = idx & 127;
    Ws2t[n * 72 + k] = f2b(Ws2_[idx]);
  }
  __syncthreads();
  float bs1_l[4];
#pragma unroll
  for (int nt = 0; nt < 4; ++nt) bs1_l[nt] = bs1_[nt * 16 + c];
  f32x4 bs2V[2];
  bs2V[0] = *(const f32x4*)&bs2_[c * 4];
  bs2V[1] = *(const f32x4*)&bs2_[64 + c * 4];
  unsigned short* sA = sAS[w];
  unsigned short* hw = hS[w];
  float* ef = (float*)sAS[w];

  for (int t = blockIdx.x * EW + w; t < ATILES; t += gridDim.x * EW) {
    const int n0 = t * TILE_M;
    if (lane < 16) dS[w][lane] = deginv[n0 + lane];
    if (lane < 48) {
      const int i3 = n0 * 3 + lane;
      v_dst[i3] = vcur[i3] + v_acc[i3] * dS[w][lane / 3];
      v_acc[i3] = 0.0f;
    }
    const f32x4* sbase = (const f32x4*)(scur + (size_t)n0 * SDIM);
#pragma unroll
    for (int i = 0; i < 4; ++i) {
      const int f = i * 128 + lane * 2;
      const f32x4 a = sbase[f], b = sbase[f + 1];
      *(short8*)&sA[(i * 4 + g) * 200 + c * 8] = pack8(a, b);
    }
#pragma unroll
    for (int i = 0; i < 4; ++i) {
      const int row = i * 4 + g;
      float* ab = agg + (size_t)(n0 + row) * HID + c * 4;
      const f32x4 av = *(const f32x4*)ab;
      const float di = dS[w][row];
      union { unsigned short u[4]; ull ll; } pk4;
      pk4.u[0] = f2b(av[0] * di); pk4.u[1] = f2b(av[1] * di);
      pk4.u[2] = f2b(av[2] * di); pk4.u[3] = f2b(av[3] * di);
      *(ull*)&sA[row * 200 + 128 + c * 4] = pk4.ll;
      *(f32x4*)ab = f32x4{0.f, 0.f, 0.f, 0.f};
    }
    f32x4 acc[4];
#pragma unroll
    for (int nt = 0; nt < 4; ++nt)
      acc[nt] = f32x4{bs1_l[nt], bs1_l[nt], bs1_l[nt], bs1_l[nt]};
#pragma unroll
    for (int kc = 0; kc < 6; ++kc) {
      const short8 af = *(const short8*)&sA[c * 200 + kc * 32 + g * 8];
#pragma unroll
      for (int nt = 0; nt < 4; ++nt) {
        const short8 bf = *(const short8*)&Ws1t[(nt * 16 + c) * 200 + kc * 32 + g * 8];
        acc[nt] = __builtin_amdgcn_mfma_f32_16x16x32_bf16(af, bf, acc[nt], 0, 0, 0);
      }
    }
#pragma unroll
    for (int nt = 0; nt < 4; ++nt)
#pragma unroll
      for (int r = 0; r < 4; ++r)
        hw[(g * 4 + r) * 72 + nt * 16 + c] = f2b(silu_f(acc[nt][r]));
    f32x4 o[8];
#pragma unroll
    for (int nt = 0; nt < 8; ++nt) o[nt] = f32x4{0.f, 0.f, 0.f, 0.f};
#pragma unroll
    for (int kc = 0; kc < 2; ++kc) {
      const short8 am = *(const short8*)&hw[c * 72 + kc * 32 + g * 8];
#pragma unroll
      for (int nt = 0; nt < 8; ++nt) {
        const short8 bf = *(const short8*)&Ws2t[(nt * 16 + c) * 72 + kc * 32 + g * 8];
        o[nt] = __builtin_amdgcn_mfma_f32_16x16x32_bf16(am, bf, o[nt], 0, 0, 0);
      }
    }
#pragma unroll
    for (int h2 = 0; h2 < 2; ++h2) {
#pragma unroll
      for (int nt = 0; nt < 4; ++nt)
#pragma unroll
        for (int r = 0; r < 4; ++r)
          ef[(g * 4 + r) * 68 + nt * 16 + c] = o[h2 * 4 + nt][r];
#pragma unroll
      for (int q = 0; q < 4; ++q) {
        const int row = q * 4 + g;
        const f32x4 val = *(const f32x4*)&ef[row * 68 + c * 4];
        const size_t gi = (size_t)(n0 + row) * SDIM + h2 * 64 + c * 4;
        const f32x4 sres = *(const f32x4*)&scur[gi];
        *(f32x4*)&s_dst[gi] = val + bs2V[h2] + sres;
      }
    }
  }
}

// ---------- software-pipelined MFMA edge kernel, templated e-state dtype ----------
// W1/We2 B-fragments hoisted to registers (96 VGPR, statically indexed);
// Weo stays in LDS (reg budget). f2b native (cvt_pk fusion).
template <typename TI, typename TO>
__global__ __launch_bounds__(ETHREADS, 1) void k_edge_mfma(
    const TI* __restrict__ e_src, TO* __restrict__ e_dst,
    const unsigned short* __restrict__ SaP, const unsigned short* __restrict__ SbP,
    const int4* __restrict__ meta, const float4* __restrict__ dynA,
    const float* __restrict__ dynB,
    const float* __restrict__ W1e,
    const float* __restrict__ w1d, const float* __restrict__ w1a,
    const float* __restrict__ We2_, const float* __restrict__ be2_,
    const float* __restrict__ Weo_, const float* __restrict__ beo_,
    const float* __restrict__ Wv_, const float* __restrict__ bv_,
    float* __restrict__ v_acc, float* __restrict__ agg) {
  constexpr bool IN16 = (sizeof(TI) == 2);
  constexpr bool OUT16 = (sizeof(TO) == 2);
  __shared__ __align__(16) unsigned short W1t[64 * 136];
  __shared__ __align__(16) unsigned short We2t[64 * 72];
  __shared__ __align__(16) unsigned short WeoT[128 * 72];
  __shared__ __align__(16) unsigned short eT[EW][TILE_M * 136];
  __shared__ __align__(16) float hm[EW][TILE_M * 68];
  __shared__ __align__(16) float sbufS[EW][2][160];

  const int tid = threadIdx.x;
  const int lane = tid & 63;
  const int w = tid >> 6;
  const int c = lane & 15;
  const int g = lane >> 4;

  for (int idx = tid; idx < 128 * 64; idx += ETHREADS) {
    const int k = idx >> 6, n = idx & 63;
    W1t[n * 136 + k] = f2b(W1e[idx]);
  }
  for (int idx = tid; idx < 64 * 64; idx += ETHREADS) {
    const int k = idx >> 6, n = idx & 63;
    We2t[n * 72 + k] = f2b(We2_[idx]);
  }
  for (int idx = tid; idx < 64 * 128; idx += ETHREADS) {
    const int k = idx >> 7, n = idx & 127;
    WeoT[n * 72 + k] = f2b(Weo_[idx]);
  }
  __syncthreads();

  // hoist W1 (16) + We2 (8) B-frags into registers — loop-invariant per lane
  short8 rW1[16], rWe2[8];
#pragma unroll
  for (int kc = 0; kc < 4; ++kc)
#pragma unroll
    for (int nt = 0; nt < 4; ++nt)
      rW1[kc * 4 + nt] = *(const short8*)&W1t[(nt * 16 + c) * 136 + kc * 32 + g * 8];
#pragma unroll
  for (int kc = 0; kc < 2; ++kc)
#pragma unroll
    for (int nt = 0; nt < 4; ++nt)
      rWe2[kc * 4 + nt] = *(const short8*)&We2t[(nt * 16 + c) * 72 + kc * 32 + g * 8];

  float w1d_l[4], w1a_l[4], be2_l[4], Wv_l[4], beo_l[8];
#pragma unroll
  for (int nt = 0; nt < 4; ++nt) {
    w1d_l[nt] = w1d[nt * 16 + c];
    w1a_l[nt] = w1a[nt * 16 + c];
    be2_l[nt] = be2_[nt * 16 + c];
    Wv_l[nt]  = Wv_[nt * 16 + c];
  }
#pragma unroll
  for (int nt = 0; nt < 8; ++nt) beo_l[nt] = beo_[nt * 16 + c];
  const float bv0 = bv_[0];

  unsigned short* eTw = eT[w];
  float* hmw = hm[w];

  // pipeline registers
  f32x4 eAf[8];
  short8 eAb[4];
  ull sabA[4], sabB[4];
  int4 metaR = {0, 0, 0, 0};
  float4 dynAR = {0.f, 0.f, 0.f, 0.f};
  float cwR = 0.f;

  const int t0 = blockIdx.x * EW + w;
  int cur = 0;

  // ---- prologue ----
  {
    float* sb0 = &sbufS[w][0][0];
    int* sbi0 = (int*)sb0;
    if (lane < 16) {
      const int pos = t0 * TILE_M + lane;
      const int4 m = meta[pos];
      const float4 da = dynA[pos];
      const float cwv = dynB[pos];
      sb0[lane] = da.w; sb0[16 + lane] = cwv; sb0[32 + lane] = __int_as_float(m.w);
      sb0[48 + lane] = da.x; sb0[64 + lane] = da.y; sb0[80 + lane] = da.z;
      sbi0[96 + lane] = m.y; sbi0[112 + lane] = m.z; sbi0[128 + lane] = m.x;
    }
#pragma unroll
    for (int i = 0; i < 4; ++i) {
      const int er = sbi0[128 + i * 4 + g];
      if constexpr (IN16) {
        eAb[i] = *((const short8*)(e_src + (size_t)er * EDIM) + c);
      } else {
        const f32x4* eb = (const f32x4*)(e_src + (size_t)er * EDIM);
        eAf[i * 2] = eb[c * 2];
        eAf[i * 2 + 1] = eb[c * 2 + 1];
      }
    }
#pragma unroll
    for (int r = 0; r < 4; ++r) {
      sabA[r] = *(const ull*)&SaP[(size_t)sbi0[96 + g * 4 + r] * 64 + c * 4];
      sabB[r] = *(const ull*)&SbP[(size_t)sbi0[112 + g * 4 + r] * 64 + c * 4];
    }
    if (t0 + TWAVES < NTILES && lane < 16) {
      const int pos = (t0 + TWAVES) * TILE_M + lane;
      metaR = meta[pos]; dynAR = dynA[pos]; cwR = dynB[pos];
    }
  }

  for (int t = t0; t < NTILES; t += TWAVES) {
    const bool hasNext = (t + TWAVES) < NTILES;
    float* sbC = &sbufS[w][cur][0];
    int* sbiC = (int*)sbC;
    float* sbN = &sbufS[w][cur ^ 1][0];
    int* sbiN = (int*)sbN;

    if (hasNext && lane < 16) {
      sbN[lane] = dynAR.w; sbN[16 + lane] = cwR; sbN[32 + lane] = __int_as_float(metaR.w);
      sbN[48 + lane] = dynAR.x; sbN[64 + lane] = dynAR.y; sbN[80 + lane] = dynAR.z;
      sbiN[96 + lane] = metaR.y; sbiN[112 + lane] = metaR.z; sbiN[128 + lane] = metaR.x;
    }

    // pack e(t) regs -> LDS
#pragma unroll
    for (int i = 0; i < 4; ++i) {
      if constexpr (IN16)
        *(short8*)&eT[w][(i * 4 + g) * 136 + c * 8] = eAb[i];
      else
        *(short8*)&eT[w][(i * 4 + g) * 136 + c * 8] = pack8(eAf[i * 2], eAf[i * 2 + 1]);
    }

    // C-init
    float dist_r[4], cw_r[4], ea_r[4];
#pragma unroll
    for (int r = 0; r < 4; ++r) {
      const int row = g * 4 + r;
      dist_r[r] = sbC[row]; cw_r[r] = sbC[16 + row]; ea_r[r] = sbC[32 + row];
    }
    f32x4 acc[4];
#pragma unroll
    for (int nt = 0; nt < 4; ++nt)
#pragma unroll
      for (int r = 0; r < 4; ++r)
        acc[nt][r] = b2f((unsigned short)(sabA[r] >> (nt * 16)))
                   + b2f((unsigned short)(sabB[r] >> (nt * 16)))
                   + dist_r[r] * w1d_l[nt] + ea_r[r] * w1a_l[nt];

    // issue gathers for t+1
    if (hasNext) {
#pragma unroll
      for (int i = 0; i < 4; ++i) {
        const int er = sbiN[128 + i * 4 + g];
        if constexpr (IN16) {
          eAb[i] = *((const short8*)(e_src + (size_t)er * EDIM) + c);
        } else {
          const f32x4* eb = (const f32x4*)(e_src + (size_t)er * EDIM);
          eAf[i * 2] = eb[c * 2];
          eAf[i * 2 + 1] = eb[c * 2 + 1];
        }
      }
#pragma unroll
      for (int r = 0; r < 4; ++r) {
        sabA[r] = *(const ull*)&SaP[(size_t)sbiN[96 + g * 4 + r] * 64 + c * 4];
        sabB[r] = *(const ull*)&SbP[(size_t)sbiN[112 + g * 4 + r] * 64 + c * 4];
      }
      if (t + 2 * TWAVES < NTILES && lane < 16) {
        const int pos = (t + 2 * TWAVES) * TILE_M + lane;
        metaR = meta[pos]; dynAR = dynA[pos]; cwR = dynB[pos];
      }
    }

    // G1 (B-frags from registers)
#pragma unroll
    for (int kc = 0; kc < 4; ++kc) {
      const short8 af = *(const short8*)&eTw[c * 136 + kc * 32 + g * 8];
#pragma unroll
      for (int nt = 0; nt < 4; ++nt)
        acc[nt] = __builtin_amdgcn_mfma_f32_16x16x32_bf16(af, rW1[kc * 4 + nt],
                                                          acc[nt], 0, 0, 0);
    }
#pragma unroll
    for (int nt = 0; nt < 4; ++nt)
#pragma unroll
      for (int r = 0; r < 4; ++r)
        hmw[(g * 4 + r) * 68 + nt * 16 + c] = silu_f(acc[nt][r]);

    // G2 (B-frags from registers)
    f32x4 acc2[4];
#pragma unroll
    for (int nt = 0; nt < 4; ++nt)
      acc2[nt] = f32x4{be2_l[nt], be2_l[nt], be2_l[nt], be2_l[nt]};
#pragma unroll
    for (int kc = 0; kc < 2; ++kc) {
      const f32x4 lo = *(const f32x4*)&hmw[c * 68 + kc * 32 + g * 8];
      const f32x4 hi = *(const f32x4*)&hmw[c * 68 + kc * 32 + g * 8 + 4];
      const short8 am = pack8(lo, hi);
#pragma unroll
      for (int nt = 0; nt < 4; ++nt)
        acc2[nt] = __builtin_amdgcn_mfma_f32_16x16x32_bf16(am, rWe2[kc * 4 + nt],
                                                           acc2[nt], 0, 0, 0);
    }
    float mval[4][4];
#pragma unroll
    for (int nt = 0; nt < 4; ++nt)
#pragma unroll
      for (int r = 0; r < 4; ++r)
        mval[nt][r] = silu_f(acc2[nt][r]) * cw_r[r];

#pragma unroll
    for (int nt = 0; nt < 4; ++nt)
#pragma unroll
      for (int r = 0; r < 4; ++r)
        hmw[(g * 4 + r) * 68 + nt * 16 + c] = mval[nt][r];

#pragma unroll
    for (int r = 0; r < 4; ++r) {
      float s = mval[0][r] * Wv_l[0];
#pragma unroll
      for (int nt = 1; nt < 4; ++nt) s = fmaf(mval[nt][r], Wv_l[nt], s);
      s += __shfl_xor(s, 1); s += __shfl_xor(s, 2);
      s += __shfl_xor(s, 4); s += __shfl_xor(s, 8);
      if (c == 0) sbC[144 + g * 4 + r] = s + bv0;
    }

    // segmented agg
    {
      float accum = 0.f;
#pragma unroll
      for (int row = 0; row < 16; ++row) {
        accum += hmw[row * 68 + lane];
        const int dd = sbiC[112 + row];
        const bool cut = (row == 15) || (sbiC[113 + row] != dd);
        if (cut) {
          atomicAdd(&agg[(size_t)dd * HID + lane], accum);
          accum = 0.f;
        }
      }
    }
    if (lane < 3) {
      float accum = 0.f;
#pragma unroll
      for (int row = 0; row < 16; ++row) {
        accum = fmaf(sbC[48 + 16 * lane + row], sbC[144 + row], accum);
        const int dd = sbiC[112 + row];
        const bool cut = (row == 15) || (sbiC[113 + row] != dd);
        if (cut) {
          atomicAdd(&v_acc[(size_t)dd * 3 + lane], accum);
          accum = 0.f;
        }
      }
    }

    // GEMMo (Weo from LDS)
    f32x4 oacc[8];
#pragma unroll
    for (int nt = 0; nt < 8; ++nt)
      oacc[nt] = f32x4{beo_l[nt], beo_l[nt], beo_l[nt], beo_l[nt]};
#pragma unroll
    for (int kc = 0; kc < 2; ++kc) {
      const f32x4 lo = *(const f32x4*)&hmw[c * 68 + kc * 32 + g * 8];
      const f32x4 hi = *(const f32x4*)&hmw[c * 68 + kc * 32 + g * 8 + 4];
      const short8 am = pack8(lo, hi);
#pragma unroll
      for (int nt = 0; nt < 8; ++nt) {
        const short8 bf = *(const short8*)&WeoT[(nt * 16 + c) * 72 + kc * 32 + g * 8];
        oacc[nt] = __builtin_amdgcn_mfma_f32_16x16x32_bf16(am, bf, oacc[nt], 0, 0, 0);
      }
    }

    // epilogue
#pragma unroll
    for (int h2 = 0; h2 < 2; ++h2) {
#pragma unroll
      for (int nt = 0; nt < 4; ++nt)
#pragma unroll
        for (int r = 0; r < 4; ++r)
          hmw[(g * 4 + r) * 68 + nt * 16 + c] = oacc[h2 * 4 + nt][r];
#pragma unroll
      for (int q = 0; q < 4; ++q) {
        const int row = q * 4 + g;
        const int er = sbiC[128 + row];
        const f32x4 val = *(const f32x4*)&hmw[row * 68 + c * 4];
        f32x4 old;
        if constexpr (IN16) {
#pragma unroll
          for (int j = 0; j < 4; ++j)
            old[j] = b2f(eTw[row * 136 + h2 * 64 + c * 4 + j]);
        } else {
          old = *(const f32x4*)&e_src[(size_t)er * EDIM + h2 * 64 + c * 4];
        }
        const f32x4 sum = val + old;
        if constexpr (OUT16) {
          union { unsigned short u[4]; ull ll; } pk4;
          pk4.u[0] = f2b(sum[0]); pk4.u[1] = f2b(sum[1]);
          pk4.u[2] = f2b(sum[2]); pk4.u[3] = f2b(sum[3]);
          *(ull*)&e_dst[(size_t)er * EDIM + h2 * 64 + c * 4] = pk4.ll;
        } else {
          *(f32x4*)&e_dst[(size_t)er * EDIM + h2 * 64 + c * 4] = sum;
        }
      }
    }
    cur ^= 1;
  }
}

extern "C" void kernel_launch(void* const* d_in, const int* in_sizes, int n_in,
                              void* d_out, int out_size, void* d_ws, size_t ws_size,
                              hipStream_t stream) {
  const float* s_in = (const float*)d_in[0];
  const float* v_in = (const float*)d_in[1];
  const float* e_in = (const float*)d_in[2];
  const int*   eidx = (const int*)d_in[3];
  const float* ead  = (const float*)d_in[4];
  const float* We1 = (const float*)d_in[7];
  const float* be1 = (const float*)d_in[8];
  const float* We2 = (const float*)d_in[9];
  const float* be2 = (const float*)d_in[10];
  const float* Weo = (const float*)d_in[11];
  const float* beo = (const float*)d_in[12];
  const float* Wv  = (const float*)d_in[13];
  const float* bv  = (const float*)d_in[14];
  const float* Ws1 = (const float*)d_in[15];
  const float* bs1 = (const float*)d_in[16];
  const float* Ws2 = (const float*)d_in[17];
  const float* bs2 = (const float*)d_in[18];

  float* out_s = (float*)d_out;                       // [N,128]
  float* out_v = out_s + (size_t)N_NODES * SDIM;      // [N,3]
  float* out_e = out_v + (size_t)N_NODES * 3;         // [E,128]

  float* ws     = (float*)d_ws;
  float* deginv = ws;                                 // N
  float* v_acc  = deginv + N_NODES;                   // 3N
  float* agg    = v_acc + (size_t)3 * N_NODES;        // 64N
  unsigned short* SaP = (unsigned short*)(agg + (size_t)64 * N_NODES);  // 64N u16
  unsigned short* SbP = SaP + (size_t)64 * N_NODES;                     // 64N u16
  int* cnt     = (int*)(SbP + (size_t)64 * N_NODES);  // N
  int* bstart  = cnt + N_NODES;                       // N
  int* cursor  = bstart + N_NODES;                    // N
  int* bsum    = cursor + N_NODES;                    // 64
  int4* meta   = (int4*)(bsum + 64);                  // E int4
  float4* dynA = (float4*)(meta + N_EDGES);           // E float4
  float* dynB  = (float*)(dynA + N_EDGES);            // E
  unsigned short* eb16 = (unsigned short*)(dynB + N_EDGES);  // E*128 u16 (LAST)

  const size_t NEED = (size_t)((char*)(eb16 + (size_t)N_EDGES * EDIM) - (char*)d_ws);
  const bool u16e = (ws_size >= NEED);

  const int* srcs = eidx;
  const int* dsts = eidx + N_EDGES;

  hipLaunchKernelGGL(k_zero, dim3(512), dim3(256), 0, stream,
                     deginv, (1 + 3 + 64) * N_NODES);
  hipLaunchKernelGGL(k_zero, dim3(64), dim3(256), 0, stream,
                     (float*)cnt, N_NODES);
  hipLaunchKernelGGL(k_cnt, dim3((N_EDGES + 255) / 256), dim3(256), 0, stream,
                     dsts, cnt, N_EDGES);
  hipLaunchKernelGGL(k_deginv_cnt, dim3((N_NODES + 255) / 256), dim3(256), 0, stream,
                     cnt, deginv, N_NODES);
  hipLaunchKernelGGL(k_scan1, dim3(SCAN_NB), dim3(256), 0, stream,
                     cnt, bstart, bsum, N_NODES);
  hipLaunchKernelGGL(k_scan2, dim3(1), dim3(64), 0, stream, bsum, SCAN_NB);
  hipLaunchKernelGGL(k_scan3, dim3((N_NODES + 255) / 256), dim3(256), 0, stream,
                     bstart, bsum, cursor, N_NODES);
  hipLaunchKernelGGL(k_scatter, dim3((N_EDGES + 255) / 256), dim3(256), 0, stream,
                     srcs, dsts, ead, cursor, meta, N_EDGES);

  hipLaunchKernelGGL(k_nodeA, dim3(512), dim3(512), 0, stream,
                     s_in, We1, be1, SaP, SbP);

  for (int i = 0; i < DEPTH; ++i) {
    const float* W1i = We1 + (size_t)i * MSG_IN * HID;
    hipLaunchKernelGGL(k_prep, dim3((N_EDGES + 255) / 256), dim3(256), 0, stream,
                       meta, (i == 0) ? v_in : out_v, dynA, dynB, N_EDGES);
#define EDGE_ARGS                                                              \
      SaP, SbP, meta, dynA, dynB,                                              \
      W1i + 256 * HID, W1i + 384 * HID, W1i + 385 * HID,                       \
      We2 + (size_t)i * HID * HID, be2 + i * HID,                              \
      Weo + (size_t)i * HID * EDIM, beo + i * EDIM,                            \
      Wv + i * HID, bv + i, v_acc, agg
    if (u16e) {
      if (i == 0)
        k_edge_mfma<float, unsigned short>
            <<<dim3(EBLOCKS), dim3(ETHREADS), 0, stream>>>(e_in, eb16, EDGE_ARGS);
      else if (i == DEPTH - 1)
        k_edge_mfma<unsigned short, float>
            <<<dim3(EBLOCKS), dim3(ETHREADS), 0, stream>>>(eb16, out_e, EDGE_ARGS);
      else
        k_edge_mfma<unsigned short, unsigned short>
            <<<dim3(EBLOCKS), dim3(ETHREADS), 0, stream>>>(eb16, eb16, EDGE_ARGS);
    } else {
      k_edge_mfma<float, float>
          <<<dim3(EBLOCKS), dim3(ETHREADS), 0, stream>>>(
              (i == 0) ? e_in : out_e, out_e, EDGE_ARGS);
    }
#undef EDGE_ARGS
    hipLaunchKernelGGL(k_nodeC, dim3(EBLOCKS), dim3(512), 0, stream,
                       (i == 0) ? s_in : out_s, out_s,
                       (i == 0) ? v_in : out_v, out_v,
                       v_acc, agg, deginv,
                       Ws1 + (size_t)i * SCAL_IN * HID, bs1 + i * HID,
                       Ws2 + (size_t)i * HID * SDIM, bs2 + i * SDIM);
    if (i + 1 < DEPTH)
      hipLaunchKernelGGL(k_nodeA, dim3(512), dim3(512), 0, stream,
                         out_s, We1 + (size_t)(i + 1) * MSG_IN * HID,
                         be1 + (i + 1) * HID, SaP, SbP);
  }
}

// Round 15
// 742.358 us; speedup vs baseline: 1.3314x; 1.3314x over previous
//
#include <hip/hip_runtime.h>
#include <math.h>

#define N_NODES 40000
#define N_EDGES 512000
#define SDIM 128
#define EDIM 128
#define HID 64
#define DEPTH 4
#define MSG_IN 386   // 2*SDIM + EDIM + 2
#define SCAL_IN 192  // SDIM + HID
#define CUTOFF 5.0f
#define EPS_D 1e-6f

#define TILE_M 16
#define EW 8
#define ETHREADS 512
#define EBLOCKS 256
#define TWAVES (EBLOCKS * EW)
#define NTILES (N_EDGES / TILE_M)   // 32000
#define ATILES (N_NODES / TILE_M)   // 2500
#define SCAN_B 1024
#define SCAN_NB ((N_NODES + SCAN_B - 1) / SCAN_B)   // 40

typedef __attribute__((ext_vector_type(8))) short short8;
typedef __attribute__((ext_vector_type(4))) float f32x4;
typedef unsigned long long ull;

__device__ __forceinline__ float silu_f(float x) { return x / (1.0f + __expf(-x)); }

// native cast -> compiler emits v_cvt_pk_bf16_f32 for adjacent pairs (RNE)
__device__ __forceinline__ unsigned short f2b(float x) {
  union { __bf16 b; unsigned short u; } v;
  v.b = (__bf16)x;
  return v.u;
}

__device__ __forceinline__ float b2f(unsigned short u) {
  union { unsigned int u32; float f; } v; v.u32 = (unsigned int)u << 16; return v.f;
}

__device__ __forceinline__ short8 pack8(f32x4 lo, f32x4 hi) {
  union { unsigned short u[8]; short8 s; } pk;
  pk.u[0] = f2b(lo[0]); pk.u[1] = f2b(lo[1]); pk.u[2] = f2b(lo[2]); pk.u[3] = f2b(lo[3]);
  pk.u[4] = f2b(hi[0]); pk.u[5] = f2b(hi[1]); pk.u[6] = f2b(hi[2]); pk.u[7] = f2b(hi[3]);
  return pk.s;
}

__global__ __launch_bounds__(256) void k_zero(float* __restrict__ p, int n) {
  int i = blockIdx.x * 256 + threadIdx.x;
  int stride = gridDim.x * 256;
  for (; i < n; i += stride) p[i] = 0.0f;
}

__global__ __launch_bounds__(256) void k_cnt(const int* __restrict__ dst,
                                             int* __restrict__ cnt, int ne) {
  int i = blockIdx.x * 256 + threadIdx.x;
  if (i < ne) atomicAdd(&cnt[dst[i]], 1);
}

__global__ __launch_bounds__(256) void k_deginv_cnt(const int* __restrict__ cnt,
                                                    float* __restrict__ deginv, int n) {
  int i = blockIdx.x * 256 + threadIdx.x;
  if (i < n) deginv[i] = 1.0f / fmaxf((float)cnt[i], 1.0f);
}

__global__ __launch_bounds__(256) void k_scan1(const int* __restrict__ cnt,
                                               int* __restrict__ bstart,
                                               int* __restrict__ bsum, int n) {
  __shared__ int tmp[SCAN_B];
  const int base = blockIdx.x * SCAN_B;
  const int tid = threadIdx.x;
  for (int i = tid; i < SCAN_B; i += 256)
    tmp[i] = (base + i < n) ? cnt[base + i] : 0;
  __syncthreads();
  for (int off = 1; off < SCAN_B; off <<= 1) {
    int vals[4];
#pragma unroll
    for (int j = 0; j < 4; ++j) {
      const int i = tid + j * 256;
      vals[j] = (i >= off) ? tmp[i - off] : 0;
    }
    __syncthreads();
#pragma unroll
    for (int j = 0; j < 4; ++j) tmp[tid + j * 256] += vals[j];
    __syncthreads();
  }
  for (int i = tid; i < SCAN_B; i += 256)
    if (base + i < n) bstart[base + i] = tmp[i] - cnt[base + i];
  if (tid == 0) bsum[blockIdx.x] = tmp[SCAN_B - 1];
}

__global__ void k_scan2(int* __restrict__ bsum, int nb) {
  if (threadIdx.x == 0) {
    int run = 0;
    for (int i = 0; i < nb; ++i) { const int v = bsum[i]; bsum[i] = run; run += v; }
  }
}

__global__ __launch_bounds__(256) void k_scan3(int* __restrict__ bstart,
                                               const int* __restrict__ bsum,
                                               int* __restrict__ cursor, int n) {
  int i = blockIdx.x * 256 + threadIdx.x;
  if (i < n) {
    const int v = bstart[i] + bsum[i >> 10];
    bstart[i] = v;
    cursor[i] = v;
  }
}

__global__ __launch_bounds__(256) void k_scatter(const int* __restrict__ srcs,
                                                 const int* __restrict__ dsts,
                                                 const float* __restrict__ ead,
                                                 int* __restrict__ cursor,
                                                 int4* __restrict__ meta, int ne) {
  int i = blockIdx.x * 256 + threadIdx.x;
  if (i < ne) {
    const int d = dsts[i];
    const int pos = atomicAdd(&cursor[d], 1);
    int4 m;
    m.x = i; m.y = srcs[i]; m.z = d; m.w = __float_as_int(ead[i]);
    meta[pos] = m;
  }
}

__global__ __launch_bounds__(256) void k_prep(const int4* __restrict__ meta,
                                              const float* __restrict__ vbuf,
                                              float4* __restrict__ dynA,
                                              float* __restrict__ dynB, int ne) {
  int i = blockIdx.x * 256 + threadIdx.x;
  if (i < ne) {
    const int4 m = meta[i];
    const float dx = vbuf[m.y * 3 + 0] - vbuf[m.z * 3 + 0];
    const float dy = vbuf[m.y * 3 + 1] - vbuf[m.z * 3 + 1];
    const float dz = vbuf[m.y * 3 + 2] - vbuf[m.z * 3 + 2];
    const float dist = sqrtf(dx * dx + dy * dy + dz * dz + EPS_D);
    const float cwv = (dist < CUTOFF)
                          ? 0.5f * (__cosf((float)M_PI / CUTOFF * dist) + 1.0f)
                          : 0.0f;
    dynA[i] = make_float4(dx, dy, dz, dist);
    dynB[i] = cwv;
  }
}

// ---------- MFMA Sa/Sb -> packed bf16 SaP/SbP[node][64], layout k=c*4+nt ----------
__global__ __launch_bounds__(512, 2) void k_nodeA(
    const float* __restrict__ s, const float* __restrict__ W1,
    const float* __restrict__ be1_,
    unsigned short* __restrict__ SaP, unsigned short* __restrict__ SbP) {
  __shared__ __align__(16) unsigned short W1abt[64 * 264];
  __shared__ __align__(16) unsigned short snS[EW][16 * 136];
  const int tid = threadIdx.x, lane = tid & 63, w = tid >> 6;
  const int c = lane & 15, g = lane >> 4;
  for (int idx = tid; idx < 256 * 64; idx += 512) {
    const int k = idx >> 6, n = idx & 63;
    W1abt[n * 264 + k] = f2b(W1[idx]);
  }
  __syncthreads();
  float be1_l[4];
#pragma unroll
  for (int nt = 0; nt < 4; ++nt) be1_l[nt] = be1_[nt * 16 + c];
  unsigned short* sn = snS[w];

  for (int t = blockIdx.x * EW + w; t < ATILES; t += gridDim.x * EW) {
    const int n0 = t * TILE_M;
    const f32x4* sbase = (const f32x4*)(s + (size_t)n0 * SDIM);
#pragma unroll
    for (int i = 0; i < 4; ++i) {
      const int f = i * 128 + lane * 2;
      const f32x4 a = sbase[f], b = sbase[f + 1];
      *(short8*)&sn[(i * 4 + g) * 136 + c * 8] = pack8(a, b);
    }
    f32x4 aA[4], aB[4];
#pragma unroll
    for (int nt = 0; nt < 4; ++nt) {
      aA[nt] = f32x4{be1_l[nt], be1_l[nt], be1_l[nt], be1_l[nt]};
      aB[nt] = f32x4{0.f, 0.f, 0.f, 0.f};
    }
#pragma unroll
    for (int kc = 0; kc < 4; ++kc) {
      const short8 af = *(const short8*)&sn[c * 136 + kc * 32 + g * 8];
#pragma unroll
      for (int nt = 0; nt < 4; ++nt) {
        const short8 bfA = *(const short8*)&W1abt[(nt * 16 + c) * 264 + kc * 32 + g * 8];
        const short8 bfB = *(const short8*)&W1abt[(nt * 16 + c) * 264 + 128 + kc * 32 + g * 8];
        aA[nt] = __builtin_amdgcn_mfma_f32_16x16x32_bf16(af, bfA, aA[nt], 0, 0, 0);
        aB[nt] = __builtin_amdgcn_mfma_f32_16x16x32_bf16(af, bfB, aB[nt], 0, 0, 0);
      }
    }
#pragma unroll
    for (int r = 0; r < 4; ++r) {
      const size_t row = (size_t)(n0 + g * 4 + r);
      const ull pa = (ull)f2b(aA[0][r]) | ((ull)f2b(aA[1][r]) << 16)
                   | ((ull)f2b(aA[2][r]) << 32) | ((ull)f2b(aA[3][r]) << 48);
      const ull pb = (ull)f2b(aB[0][r]) | ((ull)f2b(aB[1][r]) << 16)
                   | ((ull)f2b(aB[2][r]) << 32) | ((ull)f2b(aB[3][r]) << 48);
      *(ull*)&SaP[row * 64 + c * 4] = pa;
      *(ull*)&SbP[row * 64 + c * 4] = pb;
    }
  }
}

// ---------- MFMA node update (r10-r13 proven; f2b native) ----------
__global__ __launch_bounds__(512, 2) void k_nodeC(
    const float* __restrict__ scur, float* __restrict__ s_dst,
    const float* __restrict__ vcur, float* __restrict__ v_dst,
    float* __restrict__ v_acc, float* __restrict__ agg,
    const float* __restrict__ deginv,
    const float* __restrict__ Ws1_, const float* __restrict__ bs1_,
    const float* __restrict__ Ws2_, const float* __restrict__ bs2_) {
  __shared__ __align__(16) unsigned short Ws1t[64 * 200];
  __shared__ __align__(16) unsigned short Ws2t[128 * 72];
  __shared__ __align__(16) unsigned short sAS[EW][16 * 200];
  __shared__ __align__(16) unsigned short hS[EW][16 * 72];
  __shared__ float dS[EW][16];
  const int tid = threadIdx.x, lane = tid & 63, w = tid >> 6;
  const int c = lane & 15, g = lane >> 4;
  for (int idx = tid; idx < 192 * 64; idx += 512) {
    const int k = idx >> 6, n = idx & 63;
    Ws1t[n * 200 + k] = f2b(Ws1_[idx]);
  }
  for (int idx = tid; idx < 64 * 128; idx += 512) {
    const int k = idx >> 7, n = idx & 127;
    Ws2t[n * 72 + k] = f2b(Ws2_[idx]);
  }
  __syncthreads();
  float bs1_l[4];
#pragma unroll
  for (int nt = 0; nt < 4; ++nt) bs1_l[nt] = bs1_[nt * 16 + c];
  f32x4 bs2V[2];
  bs2V[0] = *(const f32x4*)&bs2_[c * 4];
  bs2V[1] = *(const f32x4*)&bs2_[64 + c * 4];
  unsigned short* sA = sAS[w];
  unsigned short* hw = hS[w];
  float* ef = (float*)sAS[w];

  for (int t = blockIdx.x * EW + w; t < ATILES; t += gridDim.x * EW) {
    const int n0 = t * TILE_M;
    if (lane < 16) dS[w][lane] = deginv[n0 + lane];
    if (lane < 48) {
      const int i3 = n0 * 3 + lane;
      v_dst[i3] = vcur[i3] + v_acc[i3] * dS[w][lane / 3];
      v_acc[i3] = 0.0f;
    }
    const f32x4* sbase = (const f32x4*)(scur + (size_t)n0 * SDIM);
#pragma unroll
    for (int i = 0; i < 4; ++i) {
      const int f = i * 128 + lane * 2;
      const f32x4 a = sbase[f], b = sbase[f + 1];
      *(short8*)&sA[(i * 4 + g) * 200 + c * 8] = pack8(a, b);
    }
#pragma unroll
    for (int i = 0; i < 4; ++i) {
      const int row = i * 4 + g;
      float* ab = agg + (size_t)(n0 + row) * HID + c * 4;
      const f32x4 av = *(const f32x4*)ab;
      const float di = dS[w][row];
      union { unsigned short u[4]; ull ll; } pk4;
      pk4.u[0] = f2b(av[0] * di); pk4.u[1] = f2b(av[1] * di);
      pk4.u[2] = f2b(av[2] * di); pk4.u[3] = f2b(av[3] * di);
      *(ull*)&sA[row * 200 + 128 + c * 4] = pk4.ll;
      *(f32x4*)ab = f32x4{0.f, 0.f, 0.f, 0.f};
    }
    f32x4 acc[4];
#pragma unroll
    for (int nt = 0; nt < 4; ++nt)
      acc[nt] = f32x4{bs1_l[nt], bs1_l[nt], bs1_l[nt], bs1_l[nt]};
#pragma unroll
    for (int kc = 0; kc < 6; ++kc) {
      const short8 af = *(const short8*)&sA[c * 200 + kc * 32 + g * 8];
#pragma unroll
      for (int nt = 0; nt < 4; ++nt) {
        const short8 bf = *(const short8*)&Ws1t[(nt * 16 + c) * 200 + kc * 32 + g * 8];
        acc[nt] = __builtin_amdgcn_mfma_f32_16x16x32_bf16(af, bf, acc[nt], 0, 0, 0);
      }
    }
#pragma unroll
    for (int nt = 0; nt < 4; ++nt)
#pragma unroll
      for (int r = 0; r < 4; ++r)
        hw[(g * 4 + r) * 72 + nt * 16 + c] = f2b(silu_f(acc[nt][r]));
    f32x4 o[8];
#pragma unroll
    for (int nt = 0; nt < 8; ++nt) o[nt] = f32x4{0.f, 0.f, 0.f, 0.f};
#pragma unroll
    for (int kc = 0; kc < 2; ++kc) {
      const short8 am = *(const short8*)&hw[c * 72 + kc * 32 + g * 8];
#pragma unroll
      for (int nt = 0; nt < 8; ++nt) {
        const short8 bf = *(const short8*)&Ws2t[(nt * 16 + c) * 72 + kc * 32 + g * 8];
        o[nt] = __builtin_amdgcn_mfma_f32_16x16x32_bf16(am, bf, o[nt], 0, 0, 0);
      }
    }
#pragma unroll
    for (int h2 = 0; h2 < 2; ++h2) {
#pragma unroll
      for (int nt = 0; nt < 4; ++nt)
#pragma unroll
        for (int r = 0; r < 4; ++r)
          ef[(g * 4 + r) * 68 + nt * 16 + c] = o[h2 * 4 + nt][r];
#pragma unroll
      for (int q = 0; q < 4; ++q) {
        const int row = q * 4 + g;
        const f32x4 val = *(const f32x4*)&ef[row * 68 + c * 4];
        const size_t gi = (size_t)(n0 + row) * SDIM + h2 * 64 + c * 4;
        const f32x4 sres = *(const f32x4*)&scur[gi];
        *(f32x4*)&s_dst[gi] = val + bs2V[h2] + sres;
      }
    }
  }
}

// ---------- software-pipelined MFMA edge kernel, templated e-state dtype ----------
// r13 structure exactly (B-frags from LDS — NO register hoisting: 512-thr builds
// are hard-capped at 128 VGPR on this toolchain, hoist spilled in r14);
// f2b native (cvt_pk fusion) kept.
template <typename TI, typename TO>
__global__ __launch_bounds__(ETHREADS, 1) void k_edge_mfma(
    const TI* __restrict__ e_src, TO* __restrict__ e_dst,
    const unsigned short* __restrict__ SaP, const unsigned short* __restrict__ SbP,
    const int4* __restrict__ meta, const float4* __restrict__ dynA,
    const float* __restrict__ dynB,
    const float* __restrict__ W1e,
    const float* __restrict__ w1d, const float* __restrict__ w1a,
    const float* __restrict__ We2_, const float* __restrict__ be2_,
    const float* __restrict__ Weo_, const float* __restrict__ beo_,
    const float* __restrict__ Wv_, const float* __restrict__ bv_,
    float* __restrict__ v_acc, float* __restrict__ agg) {
  constexpr bool IN16 = (sizeof(TI) == 2);
  constexpr bool OUT16 = (sizeof(TO) == 2);
  __shared__ __align__(16) unsigned short W1t[64 * 136];
  __shared__ __align__(16) unsigned short We2t[64 * 72];
  __shared__ __align__(16) unsigned short WeoT[128 * 72];
  __shared__ __align__(16) unsigned short eT[EW][TILE_M * 136];
  __shared__ __align__(16) float hm[EW][TILE_M * 68];
  __shared__ __align__(16) float sbufS[EW][2][160];

  const int tid = threadIdx.x;
  const int lane = tid & 63;
  const int w = tid >> 6;
  const int c = lane & 15;
  const int g = lane >> 4;

  for (int idx = tid; idx < 128 * 64; idx += ETHREADS) {
    const int k = idx >> 6, n = idx & 63;
    W1t[n * 136 + k] = f2b(W1e[idx]);
  }
  for (int idx = tid; idx < 64 * 64; idx += ETHREADS) {
    const int k = idx >> 6, n = idx & 63;
    We2t[n * 72 + k] = f2b(We2_[idx]);
  }
  for (int idx = tid; idx < 64 * 128; idx += ETHREADS) {
    const int k = idx >> 7, n = idx & 127;
    WeoT[n * 72 + k] = f2b(Weo_[idx]);
  }
  __syncthreads();

  float w1d_l[4], w1a_l[4], be2_l[4], Wv_l[4], beo_l[8];
#pragma unroll
  for (int nt = 0; nt < 4; ++nt) {
    w1d_l[nt] = w1d[nt * 16 + c];
    w1a_l[nt] = w1a[nt * 16 + c];
    be2_l[nt] = be2_[nt * 16 + c];
    Wv_l[nt]  = Wv_[nt * 16 + c];
  }
#pragma unroll
  for (int nt = 0; nt < 8; ++nt) beo_l[nt] = beo_[nt * 16 + c];
  const float bv0 = bv_[0];

  unsigned short* eTw = eT[w];
  float* hmw = hm[w];

  // pipeline registers
  f32x4 eAf[8];
  short8 eAb[4];
  ull sabA[4], sabB[4];
  int4 metaR = {0, 0, 0, 0};
  float4 dynAR = {0.f, 0.f, 0.f, 0.f};
  float cwR = 0.f;

  const int t0 = blockIdx.x * EW + w;
  int cur = 0;

  // ---- prologue ----
  {
    float* sb0 = &sbufS[w][0][0];
    int* sbi0 = (int*)sb0;
    if (lane < 16) {
      const int pos = t0 * TILE_M + lane;
      const int4 m = meta[pos];
      const float4 da = dynA[pos];
      const float cwv = dynB[pos];
      sb0[lane] = da.w; sb0[16 + lane] = cwv; sb0[32 + lane] = __int_as_float(m.w);
      sb0[48 + lane] = da.x; sb0[64 + lane] = da.y; sb0[80 + lane] = da.z;
      sbi0[96 + lane] = m.y; sbi0[112 + lane] = m.z; sbi0[128 + lane] = m.x;
    }
#pragma unroll
    for (int i = 0; i < 4; ++i) {
      const int er = sbi0[128 + i * 4 + g];
      if constexpr (IN16) {
        eAb[i] = *((const short8*)(e_src + (size_t)er * EDIM) + c);
      } else {
        const f32x4* eb = (const f32x4*)(e_src + (size_t)er * EDIM);
        eAf[i * 2] = eb[c * 2];
        eAf[i * 2 + 1] = eb[c * 2 + 1];
      }
    }
#pragma unroll
    for (int r = 0; r < 4; ++r) {
      sabA[r] = *(const ull*)&SaP[(size_t)sbi0[96 + g * 4 + r] * 64 + c * 4];
      sabB[r] = *(const ull*)&SbP[(size_t)sbi0[112 + g * 4 + r] * 64 + c * 4];
    }
    if (t0 + TWAVES < NTILES && lane < 16) {
      const int pos = (t0 + TWAVES) * TILE_M + lane;
      metaR = meta[pos]; dynAR = dynA[pos]; cwR = dynB[pos];
    }
  }

  for (int t = t0; t < NTILES; t += TWAVES) {
    const bool hasNext = (t + TWAVES) < NTILES;
    float* sbC = &sbufS[w][cur][0];
    int* sbiC = (int*)sbC;
    float* sbN = &sbufS[w][cur ^ 1][0];
    int* sbiN = (int*)sbN;

    if (hasNext && lane < 16) {
      sbN[lane] = dynAR.w; sbN[16 + lane] = cwR; sbN[32 + lane] = __int_as_float(metaR.w);
      sbN[48 + lane] = dynAR.x; sbN[64 + lane] = dynAR.y; sbN[80 + lane] = dynAR.z;
      sbiN[96 + lane] = metaR.y; sbiN[112 + lane] = metaR.z; sbiN[128 + lane] = metaR.x;
    }

    // pack e(t) regs -> LDS
#pragma unroll
    for (int i = 0; i < 4; ++i) {
      if constexpr (IN16)
        *(short8*)&eT[w][(i * 4 + g) * 136 + c * 8] = eAb[i];
      else
        *(short8*)&eT[w][(i * 4 + g) * 136 + c * 8] = pack8(eAf[i * 2], eAf[i * 2 + 1]);
    }

    // C-init
    float dist_r[4], cw_r[4], ea_r[4];
#pragma unroll
    for (int r = 0; r < 4; ++r) {
      const int row = g * 4 + r;
      dist_r[r] = sbC[row]; cw_r[r] = sbC[16 + row]; ea_r[r] = sbC[32 + row];
    }
    f32x4 acc[4];
#pragma unroll
    for (int nt = 0; nt < 4; ++nt)
#pragma unroll
      for (int r = 0; r < 4; ++r)
        acc[nt][r] = b2f((unsigned short)(sabA[r] >> (nt * 16)))
                   + b2f((unsigned short)(sabB[r] >> (nt * 16)))
                   + dist_r[r] * w1d_l[nt] + ea_r[r] * w1a_l[nt];

    // issue gathers for t+1
    if (hasNext) {
#pragma unroll
      for (int i = 0; i < 4; ++i) {
        const int er = sbiN[128 + i * 4 + g];
        if constexpr (IN16) {
          eAb[i] = *((const short8*)(e_src + (size_t)er * EDIM) + c);
        } else {
          const f32x4* eb = (const f32x4*)(e_src + (size_t)er * EDIM);
          eAf[i * 2] = eb[c * 2];
          eAf[i * 2 + 1] = eb[c * 2 + 1];
        }
      }
#pragma unroll
      for (int r = 0; r < 4; ++r) {
        sabA[r] = *(const ull*)&SaP[(size_t)sbiN[96 + g * 4 + r] * 64 + c * 4];
        sabB[r] = *(const ull*)&SbP[(size_t)sbiN[112 + g * 4 + r] * 64 + c * 4];
      }
      if (t + 2 * TWAVES < NTILES && lane < 16) {
        const int pos = (t + 2 * TWAVES) * TILE_M + lane;
        metaR = meta[pos]; dynAR = dynA[pos]; cwR = dynB[pos];
      }
    }

    // G1
#pragma unroll
    for (int kc = 0; kc < 4; ++kc) {
      const short8 af = *(const short8*)&eTw[c * 136 + kc * 32 + g * 8];
#pragma unroll
      for (int nt = 0; nt < 4; ++nt) {
        const short8 bf = *(const short8*)&W1t[(nt * 16 + c) * 136 + kc * 32 + g * 8];
        acc[nt] = __builtin_amdgcn_mfma_f32_16x16x32_bf16(af, bf, acc[nt], 0, 0, 0);
      }
    }
#pragma unroll
    for (int nt = 0; nt < 4; ++nt)
#pragma unroll
      for (int r = 0; r < 4; ++r)
        hmw[(g * 4 + r) * 68 + nt * 16 + c] = silu_f(acc[nt][r]);

    // G2
    f32x4 acc2[4];
#pragma unroll
    for (int nt = 0; nt < 4; ++nt)
      acc2[nt] = f32x4{be2_l[nt], be2_l[nt], be2_l[nt], be2_l[nt]};
#pragma unroll
    for (int kc = 0; kc < 2; ++kc) {
      const f32x4 lo = *(const f32x4*)&hmw[c * 68 + kc * 32 + g * 8];
      const f32x4 hi = *(const f32x4*)&hmw[c * 68 + kc * 32 + g * 8 + 4];
      const short8 am = pack8(lo, hi);
#pragma unroll
      for (int nt = 0; nt < 4; ++nt) {
        const short8 bf = *(const short8*)&We2t[(nt * 16 + c) * 72 + kc * 32 + g * 8];
        acc2[nt] = __builtin_amdgcn_mfma_f32_16x16x32_bf16(am, bf, acc2[nt], 0, 0, 0);
      }
    }
    float mval[4][4];
#pragma unroll
    for (int nt = 0; nt < 4; ++nt)
#pragma unroll
      for (int r = 0; r < 4; ++r)
        mval[nt][r] = silu_f(acc2[nt][r]) * cw_r[r];

#pragma unroll
    for (int nt = 0; nt < 4; ++nt)
#pragma unroll
      for (int r = 0; r < 4; ++r)
        hmw[(g * 4 + r) * 68 + nt * 16 + c] = mval[nt][r];

#pragma unroll
    for (int r = 0; r < 4; ++r) {
      float s = mval[0][r] * Wv_l[0];
#pragma unroll
      for (int nt = 1; nt < 4; ++nt) s = fmaf(mval[nt][r], Wv_l[nt], s);
      s += __shfl_xor(s, 1); s += __shfl_xor(s, 2);
      s += __shfl_xor(s, 4); s += __shfl_xor(s, 8);
      if (c == 0) sbC[144 + g * 4 + r] = s + bv0;
    }

    // segmented agg
    {
      float accum = 0.f;
#pragma unroll
      for (int row = 0; row < 16; ++row) {
        accum += hmw[row * 68 + lane];
        const int dd = sbiC[112 + row];
        const bool cut = (row == 15) || (sbiC[113 + row] != dd);
        if (cut) {
          atomicAdd(&agg[(size_t)dd * HID + lane], accum);
          accum = 0.f;
        }
      }
    }
    if (lane < 3) {
      float accum = 0.f;
#pragma unroll
      for (int row = 0; row < 16; ++row) {
        accum = fmaf(sbC[48 + 16 * lane + row], sbC[144 + row], accum);
        const int dd = sbiC[112 + row];
        const bool cut = (row == 15) || (sbiC[113 + row] != dd);
        if (cut) {
          atomicAdd(&v_acc[(size_t)dd * 3 + lane], accum);
          accum = 0.f;
        }
      }
    }

    // GEMMo
    f32x4 oacc[8];
#pragma unroll
    for (int nt = 0; nt < 8; ++nt)
      oacc[nt] = f32x4{beo_l[nt], beo_l[nt], beo_l[nt], beo_l[nt]};
#pragma unroll
    for (int kc = 0; kc < 2; ++kc) {
      const f32x4 lo = *(const f32x4*)&hmw[c * 68 + kc * 32 + g * 8];
      const f32x4 hi = *(const f32x4*)&hmw[c * 68 + kc * 32 + g * 8 + 4];
      const short8 am = pack8(lo, hi);
#pragma unroll
      for (int nt = 0; nt < 8; ++nt) {
        const short8 bf = *(const short8*)&WeoT[(nt * 16 + c) * 72 + kc * 32 + g * 8];
        oacc[nt] = __builtin_amdgcn_mfma_f32_16x16x32_bf16(am, bf, oacc[nt], 0, 0, 0);
      }
    }

    // epilogue
#pragma unroll
    for (int h2 = 0; h2 < 2; ++h2) {
#pragma unroll
      for (int nt = 0; nt < 4; ++nt)
#pragma unroll
        for (int r = 0; r < 4; ++r)
          hmw[(g * 4 + r) * 68 + nt * 16 + c] = oacc[h2 * 4 + nt][r];
#pragma unroll
      for (int q = 0; q < 4; ++q) {
        const int row = q * 4 + g;
        const int er = sbiC[128 + row];
        const f32x4 val = *(const f32x4*)&hmw[row * 68 + c * 4];
        f32x4 old;
        if constexpr (IN16) {
#pragma unroll
          for (int j = 0; j < 4; ++j)
            old[j] = b2f(eTw[row * 136 + h2 * 64 + c * 4 + j]);
        } else {
          old = *(const f32x4*)&e_src[(size_t)er * EDIM + h2 * 64 + c * 4];
        }
        const f32x4 sum = val + old;
        if constexpr (OUT16) {
          union { unsigned short u[4]; ull ll; } pk4;
          pk4.u[0] = f2b(sum[0]); pk4.u[1] = f2b(sum[1]);
          pk4.u[2] = f2b(sum[2]); pk4.u[3] = f2b(sum[3]);
          *(ull*)&e_dst[(size_t)er * EDIM + h2 * 64 + c * 4] = pk4.ll;
        } else {
          *(f32x4*)&e_dst[(size_t)er * EDIM + h2 * 64 + c * 4] = sum;
        }
      }
    }
    cur ^= 1;
  }
}

extern "C" void kernel_launch(void* const* d_in, const int* in_sizes, int n_in,
                              void* d_out, int out_size, void* d_ws, size_t ws_size,
                              hipStream_t stream) {
  const float* s_in = (const float*)d_in[0];
  const float* v_in = (const float*)d_in[1];
  const float* e_in = (const float*)d_in[2];
  const int*   eidx = (const int*)d_in[3];
  const float* ead  = (const float*)d_in[4];
  const float* We1 = (const float*)d_in[7];
  const float* be1 = (const float*)d_in[8];
  const float* We2 = (const float*)d_in[9];
  const float* be2 = (const float*)d_in[10];
  const float* Weo = (const float*)d_in[11];
  const float* beo = (const float*)d_in[12];
  const float* Wv  = (const float*)d_in[13];
  const float* bv  = (const float*)d_in[14];
  const float* Ws1 = (const float*)d_in[15];
  const float* bs1 = (const float*)d_in[16];
  const float* Ws2 = (const float*)d_in[17];
  const float* bs2 = (const float*)d_in[18];

  float* out_s = (float*)d_out;                       // [N,128]
  float* out_v = out_s + (size_t)N_NODES * SDIM;      // [N,3]
  float* out_e = out_v + (size_t)N_NODES * 3;         // [E,128]

  float* ws     = (float*)d_ws;
  float* deginv = ws;                                 // N
  float* v_acc  = deginv + N_NODES;                   // 3N
  float* agg    = v_acc + (size_t)3 * N_NODES;        // 64N
  unsigned short* SaP = (unsigned short*)(agg + (size_t)64 * N_NODES);  // 64N u16
  unsigned short* SbP = SaP + (size_t)64 * N_NODES;                     // 64N u16
  int* cnt     = (int*)(SbP + (size_t)64 * N_NODES);  // N
  int* bstart  = cnt + N_NODES;                       // N
  int* cursor  = bstart + N_NODES;                    // N
  int* bsum    = cursor + N_NODES;                    // 64
  int4* meta   = (int4*)(bsum + 64);                  // E int4
  float4* dynA = (float4*)(meta + N_EDGES);           // E float4
  float* dynB  = (float*)(dynA + N_EDGES);            // E
  unsigned short* eb16 = (unsigned short*)(dynB + N_EDGES);  // E*128 u16 (LAST)

  const size_t NEED = (size_t)((char*)(eb16 + (size_t)N_EDGES * EDIM) - (char*)d_ws);
  const bool u16e = (ws_size >= NEED);

  const int* srcs = eidx;
  const int* dsts = eidx + N_EDGES;

  hipLaunchKernelGGL(k_zero, dim3(512), dim3(256), 0, stream,
                     deginv, (1 + 3 + 64) * N_NODES);
  hipLaunchKernelGGL(k_zero, dim3(64), dim3(256), 0, stream,
                     (float*)cnt, N_NODES);
  hipLaunchKernelGGL(k_cnt, dim3((N_EDGES + 255) / 256), dim3(256), 0, stream,
                     dsts, cnt, N_EDGES);
  hipLaunchKernelGGL(k_deginv_cnt, dim3((N_NODES + 255) / 256), dim3(256), 0, stream,
                     cnt, deginv, N_NODES);
  hipLaunchKernelGGL(k_scan1, dim3(SCAN_NB), dim3(256), 0, stream,
                     cnt, bstart, bsum, N_NODES);
  hipLaunchKernelGGL(k_scan2, dim3(1), dim3(64), 0, stream, bsum, SCAN_NB);
  hipLaunchKernelGGL(k_scan3, dim3((N_NODES + 255) / 256), dim3(256), 0, stream,
                     bstart, bsum, cursor, N_NODES);
  hipLaunchKernelGGL(k_scatter, dim3((N_EDGES + 255) / 256), dim3(256), 0, stream,
                     srcs, dsts, ead, cursor, meta, N_EDGES);

  hipLaunchKernelGGL(k_nodeA, dim3(512), dim3(512), 0, stream,
                     s_in, We1, be1, SaP, SbP);

  for (int i = 0; i < DEPTH; ++i) {
    const float* W1i = We1 + (size_t)i * MSG_IN * HID;
    hipLaunchKernelGGL(k_prep, dim3((N_EDGES + 255) / 256), dim3(256), 0, stream,
                       meta, (i == 0) ? v_in : out_v, dynA, dynB, N_EDGES);
#define EDGE_ARGS                                                              \
      SaP, SbP, meta, dynA, dynB,                                              \
      W1i + 256 * HID, W1i + 384 * HID, W1i + 385 * HID,                       \
      We2 + (size_t)i * HID * HID, be2 + i * HID,                              \
      Weo + (size_t)i * HID * EDIM, beo + i * EDIM,                            \
      Wv + i * HID, bv + i, v_acc, agg
    if (u16e) {
      if (i == 0)
        k_edge_mfma<float, unsigned short>
            <<<dim3(EBLOCKS), dim3(ETHREADS), 0, stream>>>(e_in, eb16, EDGE_ARGS);
      else if (i == DEPTH - 1)
        k_edge_mfma<unsigned short, float>
            <<<dim3(EBLOCKS), dim3(ETHREADS), 0, stream>>>(eb16, out_e, EDGE_ARGS);
      else
        k_edge_mfma<unsigned short, unsigned short>
            <<<dim3(EBLOCKS), dim3(ETHREADS), 0, stream>>>(eb16, eb16, EDGE_ARGS);
    } else {
      k_edge_mfma<float, float>
          <<<dim3(EBLOCKS), dim3(ETHREADS), 0, stream>>>(
              (i == 0) ? e_in : out_e, out_e, EDGE_ARGS);
    }
#undef EDGE_ARGS
    hipLaunchKernelGGL(k_nodeC, dim3(EBLOCKS), dim3(512), 0, stream,
                       (i == 0) ? s_in : out_s, out_s,
                       (i == 0) ? v_in : out_v, out_v,
                       v_acc, agg, deginv,
                       Ws1 + (size_t)i * SCAL_IN * HID, bs1 + i * HID,
                       Ws2 + (size_t)i * HID * SDIM, bs2 + i * SDIM);
    if (i + 1 < DEPTH)
      hipLaunchKernelGGL(k_nodeA, dim3(512), dim3(512), 0, stream,
                         out_s, We1 + (size_t)(i + 1) * MSG_IN * HID,
                         be1 + (i + 1) * HID, SaP, SbP);
  }
}